// Round 6
// baseline (930.725 us; speedup 1.0000x reference)
//
#include <hip/hip_runtime.h>
#include <hip/hip_bf16.h>

// Problem constants (from reference setup_inputs)
#define N_NODES 16384
#define FM      256
#define NF      (N_NODES * FM)          // 4,194,304 floats per branch tensor
#define NF4     (NF / 4)                // float4 count

// ---------------------------------------------------------------------------
// Init: dinv3 = 1.0 (self-loop weight), edge-count histograms = 0, pooled = 0
// ---------------------------------------------------------------------------
__global__ void init_kernel(float* __restrict__ dinv3, int* __restrict__ cnt3,
                            float* __restrict__ pooled) {
    int i = blockIdx.x * blockDim.x + threadIdx.x;
    int n3 = 3 * N_NODES;
    if (i < n3) {
        dinv3[i] = 1.0f;
        cnt3[i] = 0;
    } else if (i < n3 + 6) {
        pooled[i - n3] = 0.0f;
    }
}

__global__ void deg_edges_kernel(const int* __restrict__ dst,
                                 const float* __restrict__ ew,
                                 float* __restrict__ deg,
                                 int* __restrict__ cnt, int E) {
    int e = blockIdx.x * blockDim.x + threadIdx.x;
    if (e < E) {
        int d = dst[e];
        atomicAdd(&deg[d], ew[e]);
        atomicAdd(&cnt[d], 1);
    }
}

__global__ void deg_finish_kernel(float* __restrict__ deg, int n3) {
    int i = blockIdx.x * blockDim.x + threadIdx.x;
    if (i < n3) deg[i] = rsqrtf(deg[i]);   // deg >= 1 always (self loop)
}

// ---------------------------------------------------------------------------
// Exclusive prefix sum of 16384 counts -> row_start[16385], cursor[16384]
// Single block of 1024 threads, 16 elements per thread.
// ---------------------------------------------------------------------------
__global__ __launch_bounds__(1024) void scan_kernel(const int* __restrict__ cnt,
                                                    int* __restrict__ row_start,
                                                    int* __restrict__ cursor) {
    __shared__ int part[1024];
    int t = threadIdx.x;
    int base = t * 16;
    int local[16];
    int s = 0;
#pragma unroll
    for (int i = 0; i < 16; ++i) { local[i] = cnt[base + i]; s += local[i]; }
    part[t] = s;
    __syncthreads();
    for (int off = 1; off < 1024; off <<= 1) {
        int v = (t >= off) ? part[t - off] : 0;
        __syncthreads();
        part[t] += v;
        __syncthreads();
    }
    int pre = (t > 0) ? part[t - 1] : 0;
#pragma unroll
    for (int i = 0; i < 16; ++i) {
        row_start[base + i] = pre;
        cursor[base + i] = pre;
        pre += local[i];
    }
    if (t == 1023) row_start[N_NODES] = pre;
}

// Scatter edges into CSR slots; precompute norm = dinv[s]*w*dinv[d].
__global__ void scatter_kernel(const int* __restrict__ src,
                               const int* __restrict__ dst,
                               const float* __restrict__ ew,
                               const float* __restrict__ dinv,
                               int* __restrict__ cursor,
                               int* __restrict__ csr_src,
                               float* __restrict__ csr_norm, int E) {
    int e = blockIdx.x * blockDim.x + threadIdx.x;
    if (e >= E) return;
    int s = src[e], d = dst[e];
    int pos = atomicAdd(&cursor[d], 1);
    csr_src[pos] = s;
    csr_norm[pos] = dinv[s] * ew[e] * dinv[d];
}

// ---------------------------------------------------------------------------
// fp32 GEMM: C[M,256] = A[M,256] @ B[256,256], all row-major.
// 128x64 tile, BK=16, 256 threads, 8x4 micro-tile per thread.
// (32 FMAs per 3 LDS b128 reads vs previous 16 per 2 — higher ALU density)
// ---------------------------------------------------------------------------
__global__ __launch_bounds__(256) void gemm256_kernel(const float* __restrict__ A,
                                                      const float* __restrict__ B,
                                                      float* __restrict__ C) {
    const int K = 256, N = 256;
    __shared__ float As[16][128];
    __shared__ float Bs[16][64];

    int tid = threadIdx.x;
    int tx = tid & 15;          // n-direction (x4 cols)
    int ty = tid >> 4;          // m-direction (x8 rows)
    int bm = blockIdx.x * 128;
    int bn = blockIdx.y * 64;

    float acc[8][4] = {};

    for (int k0 = 0; k0 < K; k0 += 16) {
        {
            // A tile: 128 rows x 16 k. Each thread: one row, 8 consecutive k.
            int arow = tid & 127;
            int akq = (tid >> 7) * 8;
            const float* ap = &A[(size_t)(bm + arow) * K + k0 + akq];
            float4 a0 = *(const float4*)ap;
            float4 a1 = *(const float4*)(ap + 4);
            As[akq + 0][arow] = a0.x;
            As[akq + 1][arow] = a0.y;
            As[akq + 2][arow] = a0.z;
            As[akq + 3][arow] = a0.w;
            As[akq + 4][arow] = a1.x;
            As[akq + 5][arow] = a1.y;
            As[akq + 6][arow] = a1.z;
            As[akq + 7][arow] = a1.w;
            // B tile: 16 k x 64 n. Each thread: one k row, 4 consecutive n.
            int krow = tid >> 4;
            int nq = (tid & 15) * 4;
            *(float4*)&Bs[krow][nq] = *(const float4*)&B[(size_t)(k0 + krow) * N + bn + nq];
        }
        __syncthreads();
#pragma unroll
        for (int k = 0; k < 16; ++k) {
            float4 a0 = *(const float4*)&As[k][ty * 8];
            float4 a1 = *(const float4*)&As[k][ty * 8 + 4];
            float4 bv = *(const float4*)&Bs[k][tx * 4];
            acc[0][0] += a0.x * bv.x; acc[0][1] += a0.x * bv.y;
            acc[0][2] += a0.x * bv.z; acc[0][3] += a0.x * bv.w;
            acc[1][0] += a0.y * bv.x; acc[1][1] += a0.y * bv.y;
            acc[1][2] += a0.y * bv.z; acc[1][3] += a0.y * bv.w;
            acc[2][0] += a0.z * bv.x; acc[2][1] += a0.z * bv.y;
            acc[2][2] += a0.z * bv.z; acc[2][3] += a0.z * bv.w;
            acc[3][0] += a0.w * bv.x; acc[3][1] += a0.w * bv.y;
            acc[3][2] += a0.w * bv.z; acc[3][3] += a0.w * bv.w;
            acc[4][0] += a1.x * bv.x; acc[4][1] += a1.x * bv.y;
            acc[4][2] += a1.x * bv.z; acc[4][3] += a1.x * bv.w;
            acc[5][0] += a1.y * bv.x; acc[5][1] += a1.y * bv.y;
            acc[5][2] += a1.y * bv.z; acc[5][3] += a1.y * bv.w;
            acc[6][0] += a1.z * bv.x; acc[6][1] += a1.z * bv.y;
            acc[6][2] += a1.z * bv.z; acc[6][3] += a1.z * bv.w;
            acc[7][0] += a1.w * bv.x; acc[7][1] += a1.w * bv.y;
            acc[7][2] += a1.w * bv.z; acc[7][3] += a1.w * bv.w;
        }
        __syncthreads();
    }
#pragma unroll
    for (int i = 0; i < 8; ++i) {
        float4 v = make_float4(acc[i][0], acc[i][1], acc[i][2], acc[i][3]);
        *(float4*)&C[(size_t)(bm + ty * 8 + i) * N + bn + tx * 4] = v;
    }
}

// ---------------------------------------------------------------------------
// Fused GCN aggregation (CSR, gather-by-destination):
// out[d][:] = relu( b + dinv[d]^2 * h[d][:] + sum_j norm_j * h[src_j][:] )
// One wave per node; lane l owns float4 l of the 256-wide feature row.
// Unroll-4 with two independent accumulator chains for VMEM/FMA ILP.
// ---------------------------------------------------------------------------
__global__ __launch_bounds__(256) void gcn_aggregate_csr(const float* __restrict__ h,
                                                         const int* __restrict__ row_start,
                                                         const int* __restrict__ csr_src,
                                                         const float* __restrict__ csr_norm,
                                                         const float* __restrict__ dinv,
                                                         const float* __restrict__ bias,
                                                         float* __restrict__ out) {
    int node = blockIdx.x * 4 + (threadIdx.x >> 6);
    int lane = threadIdx.x & 63;
    const float4* hp = (const float4*)h;

    float di = dinv[node];
    float sw = di * di;
    float4 v = hp[(size_t)node * 64 + lane];
    float4 accA = make_float4(v.x * sw, v.y * sw, v.z * sw, v.w * sw);
    float4 accB = make_float4(0.0f, 0.0f, 0.0f, 0.0f);

    int beg = row_start[node];
    int end = row_start[node + 1];
    int j = beg;
    for (; j + 3 < end; j += 4) {
        int s0 = csr_src[j];
        int s1 = csr_src[j + 1];
        int s2 = csr_src[j + 2];
        int s3 = csr_src[j + 3];
        float w0 = csr_norm[j];
        float w1 = csr_norm[j + 1];
        float w2 = csr_norm[j + 2];
        float w3 = csr_norm[j + 3];
        float4 v0 = hp[(size_t)s0 * 64 + lane];
        float4 v1 = hp[(size_t)s1 * 64 + lane];
        float4 v2 = hp[(size_t)s2 * 64 + lane];
        float4 v3 = hp[(size_t)s3 * 64 + lane];
        accA.x += w0 * v0.x + w1 * v1.x;
        accA.y += w0 * v0.y + w1 * v1.y;
        accA.z += w0 * v0.z + w1 * v1.z;
        accA.w += w0 * v0.w + w1 * v1.w;
        accB.x += w2 * v2.x + w3 * v3.x;
        accB.y += w2 * v2.y + w3 * v3.y;
        accB.z += w2 * v2.z + w3 * v3.z;
        accB.w += w2 * v2.w + w3 * v3.w;
    }
    for (; j < end; ++j) {
        int s0 = csr_src[j];
        float w0 = csr_norm[j];
        float4 v0 = hp[(size_t)s0 * 64 + lane];
        accA.x += w0 * v0.x;
        accA.y += w0 * v0.y;
        accA.z += w0 * v0.z;
        accA.w += w0 * v0.w;
    }
    float4 bb = ((const float4*)bias)[lane];
    float4 acc;
    acc.x = fmaxf(accA.x + accB.x + bb.x, 0.0f);
    acc.y = fmaxf(accA.y + accB.y + bb.y, 0.0f);
    acc.z = fmaxf(accA.z + accB.z + bb.z, 0.0f);
    acc.w = fmaxf(accA.w + accB.w + bb.w, 0.0f);
    ((float4*)out)[(size_t)node * 64 + lane] = acc;
}

// ---------------------------------------------------------------------------
// SE attention
// ---------------------------------------------------------------------------
__global__ __launch_bounds__(256) void reduce_branch_kernel(const float* __restrict__ br,
                                                            float* __restrict__ pooled) {
    int c = blockIdx.y;
    const float4* p = (const float4*)(br + (size_t)c * NF + (size_t)blockIdx.x * 16384);
    float s = 0.0f;
#pragma unroll
    for (int i = 0; i < 16; ++i) {
        float4 v = p[threadIdx.x + i * 256];
        s += v.x + v.y + v.z + v.w;
    }
    for (int o = 32; o > 0; o >>= 1) s += __shfl_down(s, o);
    __shared__ float wsum[4];
    if ((threadIdx.x & 63) == 0) wsum[threadIdx.x >> 6] = s;
    __syncthreads();
    if (threadIdx.x == 0)
        atomicAdd(&pooled[c], wsum[0] + wsum[1] + wsum[2] + wsum[3]);
}

__global__ void se_kernel(const float* __restrict__ pooled_sum,
                          const float* __restrict__ fc1_w, const float* __restrict__ fc1_b,
                          const float* __restrict__ fc2_w, const float* __restrict__ fc2_b,
                          float* __restrict__ att) {
    __shared__ float p[6];
    __shared__ float hbuf[30];
    int t = threadIdx.x;
    if (t < 6) p[t] = pooled_sum[t] * (1.0f / ((float)N_NODES * (float)FM));
    __syncthreads();
    if (t < 30) {
        float a = fc1_b[t];
#pragma unroll
        for (int c = 0; c < 6; ++c) a += fc1_w[t * 6 + c] * p[c];
        hbuf[t] = fmaxf(a, 0.0f);
    }
    __syncthreads();
    if (t < 6) {
        float a = fc2_b[t];
#pragma unroll
        for (int j = 0; j < 30; ++j) a += fc2_w[t * 30 + j] * hbuf[j];
        att[t] = 1.0f / (1.0f + expf(-a));
    }
}

// out[n][f] = sum_c cnn_w[c] * relu(att[c] * br_c[n][f]) + cnn_b
__global__ void combine_kernel(const float* __restrict__ br,
                               const float* __restrict__ att,
                               const float* __restrict__ cnn_w,
                               const float* __restrict__ cnn_b,
                               float* __restrict__ out, int total4) {
    int i = blockIdx.x * blockDim.x + threadIdx.x;
    if (i >= total4) return;
    float a[6], w[6];
#pragma unroll
    for (int c = 0; c < 6; ++c) { a[c] = att[c]; w[c] = cnn_w[c]; }
    float cb = cnn_b[0];
    float4 acc = make_float4(cb, cb, cb, cb);
#pragma unroll
    for (int c = 0; c < 6; ++c) {
        float4 v = ((const float4*)(br + (size_t)c * NF))[i];
        acc.x += w[c] * fmaxf(a[c] * v.x, 0.0f);
        acc.y += w[c] * fmaxf(a[c] * v.y, 0.0f);
        acc.z += w[c] * fmaxf(a[c] * v.z, 0.0f);
        acc.w += w[c] * fmaxf(a[c] * v.w, 0.0f);
    }
    ((float4*)out)[i] = acc;
}

// ---------------------------------------------------------------------------
// Host orchestration
// ---------------------------------------------------------------------------

static void run_conv(const float* in, const float* W, const float* b,
                     const int* row_start, const int* csr_src, const float* csr_norm,
                     const float* dinv, float* h_scratch, float* out,
                     hipStream_t stream) {
    dim3 ggrid(N_NODES / 128, FM / 64);
    gemm256_kernel<<<ggrid, 256, 0, stream>>>(in, W, h_scratch);
    gcn_aggregate_csr<<<N_NODES / 4, 256, 0, stream>>>(h_scratch, row_start, csr_src,
                                                       csr_norm, dinv, b, out);
}

extern "C" void kernel_launch(void* const* d_in, const int* in_sizes, int n_in,
                              void* d_out, int out_size, void* d_ws, size_t ws_size,
                              hipStream_t stream) {
    const float* x      = (const float*)d_in[0];
    const int*   ed_f   = (const int*)d_in[1];
    const float* ew_f   = (const float*)d_in[2];
    const int*   ed_s   = (const int*)d_in[3];
    const float* ew_s   = (const float*)d_in[4];
    const int*   ed_g   = (const int*)d_in[5];
    const float* ew_g   = (const float*)d_in[6];
    const float* Wf1 = (const float*)d_in[7];  const float* bf1 = (const float*)d_in[8];
    const float* Wf2 = (const float*)d_in[9];  const float* bf2 = (const float*)d_in[10];
    const float* Ws1 = (const float*)d_in[11]; const float* bs1 = (const float*)d_in[12];
    const float* Ws2 = (const float*)d_in[13]; const float* bs2 = (const float*)d_in[14];
    const float* Wg1 = (const float*)d_in[15]; const float* bg1 = (const float*)d_in[16];
    const float* Wg2 = (const float*)d_in[17]; const float* bg2 = (const float*)d_in[18];
    const float* fc1_w = (const float*)d_in[19]; const float* fc1_b = (const float*)d_in[20];
    const float* fc2_w = (const float*)d_in[21]; const float* fc2_b = (const float*)d_in[22];
    const float* cnn_w = (const float*)d_in[23]; const float* cnn_b = (const float*)d_in[24];

    const int E = in_sizes[1] / 2;   // 524288

    // Workspace layout (floats/ints, 4B elements):
    float* ws = (float*)d_ws;
    float* br = ws;                                    // 6 * NF floats
    float* dinv3  = ws + (size_t)6 * NF;               // 3 * N_NODES
    float* pooled = dinv3 + 3 * N_NODES;               // 6
    float* att    = pooled + 6;                        // 6 (+4 pad)
    int*   cnt3      = (int*)(att + 10);               // 3 * N_NODES
    int*   cursor3   = cnt3 + 3 * N_NODES;             // 3 * N_NODES
    int*   rowstart3 = cursor3 + 3 * N_NODES;          // 3 * (N_NODES+1) (+pad)
    int*   csr_src3  = rowstart3 + 3 * (N_NODES + 2);  // 3 * E
    float* csr_norm3 = (float*)(csr_src3 + (size_t)3 * E);  // 3 * E

    float* dinv_set[3]   = { dinv3, dinv3 + N_NODES, dinv3 + 2 * N_NODES };
    int*   cnt_set[3]    = { cnt3, cnt3 + N_NODES, cnt3 + 2 * N_NODES };
    int*   cursor_set[3] = { cursor3, cursor3 + N_NODES, cursor3 + 2 * N_NODES };
    int*   rs_set[3]     = { rowstart3, rowstart3 + (N_NODES + 2),
                             rowstart3 + 2 * (N_NODES + 2) };
    int*   csrc_set[3]   = { csr_src3, csr_src3 + E, csr_src3 + 2 * E };
    float* cnorm_set[3]  = { csr_norm3, csr_norm3 + E, csr_norm3 + 2 * E };
    const int*   ed_set[3] = { ed_f, ed_s, ed_g };
    const float* ew_set[3] = { ew_f, ew_s, ew_g };

    float* f1 = br + (size_t)0 * NF;
    float* f2 = br + (size_t)1 * NF;
    float* s1 = br + (size_t)2 * NF;
    float* s2 = br + (size_t)3 * NF;
    float* g1 = br + (size_t)4 * NF;
    float* g2 = br + (size_t)5 * NF;

    float* h = (float*)d_out;     // GEMM scratch; fully overwritten by combine

    // --- init + degree + CSR build for the 3 edge sets ---
    int n3 = 3 * N_NODES;
    init_kernel<<<(n3 + 6 + 255) / 256, 256, 0, stream>>>(dinv3, cnt3, pooled);
    for (int t = 0; t < 3; ++t)
        deg_edges_kernel<<<(E + 255) / 256, 256, 0, stream>>>(ed_set[t] + E, ew_set[t],
                                                              dinv_set[t], cnt_set[t], E);
    deg_finish_kernel<<<(n3 + 255) / 256, 256, 0, stream>>>(dinv3, n3);
    for (int t = 0; t < 3; ++t) {
        scan_kernel<<<1, 1024, 0, stream>>>(cnt_set[t], rs_set[t], cursor_set[t]);
        scatter_kernel<<<(E + 255) / 256, 256, 0, stream>>>(ed_set[t], ed_set[t] + E,
                                                            ew_set[t], dinv_set[t],
                                                            cursor_set[t], csrc_set[t],
                                                            cnorm_set[t], E);
    }

    // --- six GCN convs ---
    run_conv(x,  Wf1, bf1, rs_set[0], csrc_set[0], cnorm_set[0], dinv_set[0], h, f1, stream);
    run_conv(f1, Wf2, bf2, rs_set[0], csrc_set[0], cnorm_set[0], dinv_set[0], h, f2, stream);
    run_conv(x,  Ws1, bs1, rs_set[1], csrc_set[1], cnorm_set[1], dinv_set[1], h, s1, stream);
    run_conv(s1, Ws2, bs2, rs_set[1], csrc_set[1], cnorm_set[1], dinv_set[1], h, s2, stream);
    run_conv(x,  Wg1, bg1, rs_set[2], csrc_set[2], cnorm_set[2], dinv_set[2], h, g1, stream);
    run_conv(g1, Wg2, bg2, rs_set[2], csrc_set[2], cnorm_set[2], dinv_set[2], h, g2, stream);

    // --- SE attention ---
    dim3 rgrid(256, 6);
    reduce_branch_kernel<<<rgrid, 256, 0, stream>>>(br, pooled);
    se_kernel<<<1, 64, 0, stream>>>(pooled, fc1_w, fc1_b, fc2_w, fc2_b, att);

    // --- final 1x1 conv combine ---
    combine_kernel<<<NF4 / 256, 256, 0, stream>>>(br, att, cnn_w, cnn_b,
                                                  (float*)d_out, NF4);
}

// Round 8
// 608.472 us; speedup vs baseline: 1.5296x; 1.5296x over previous
//
#include <hip/hip_runtime.h>
#include <hip/hip_bf16.h>

// Problem constants (from reference setup_inputs)
#define N_NODES 16384
#define FM      256
#define NF      (N_NODES * FM)          // 4,194,304 floats per branch tensor
#define NF4     (NF / 4)                // float4 count

typedef __attribute__((ext_vector_type(8))) short short8;
typedef __attribute__((ext_vector_type(4))) float f32x4;

__device__ inline ushort f2bf(float f) {            // fp32 -> bf16 (RNE)
    uint u = __float_as_uint(f);
    return (ushort)((u + 0x7FFFu + ((u >> 16) & 1u)) >> 16);
}
__device__ inline uint pack2bf(float a, float b) {
    return (uint)f2bf(a) | ((uint)f2bf(b) << 16);
}
__device__ inline float bf2f(ushort u) { return __uint_as_float(((uint)u) << 16); }

// ---------------------------------------------------------------------------
// Init: dinv3 = 1.0 (self-loop weight), edge-count histograms = 0, pooled = 0
// ---------------------------------------------------------------------------
__global__ void init_kernel(float* __restrict__ dinv3, int* __restrict__ cnt3,
                            float* __restrict__ pooled) {
    int i = blockIdx.x * blockDim.x + threadIdx.x;
    int n3 = 3 * N_NODES;
    if (i < n3) {
        dinv3[i] = 1.0f;
        cnt3[i] = 0;
    } else if (i < n3 + 6) {
        pooled[i - n3] = 0.0f;
    }
}

// One launch, grid.y = edge-set index.
__global__ void deg_edges_all(const int* __restrict__ d0, const int* __restrict__ d1,
                              const int* __restrict__ d2,
                              const float* __restrict__ e0, const float* __restrict__ e1,
                              const float* __restrict__ e2,
                              float* __restrict__ deg3, int* __restrict__ cnt3, int E) {
    int t = blockIdx.y;
    const int* dst = (t == 0) ? d0 : (t == 1) ? d1 : d2;
    const float* ew = (t == 0) ? e0 : (t == 1) ? e1 : e2;
    float* deg = deg3 + t * N_NODES;
    int* cnt = cnt3 + t * N_NODES;
    int e = blockIdx.x * blockDim.x + threadIdx.x;
    if (e < E) {
        int d = dst[e];
        atomicAdd(&deg[d], ew[e]);
        atomicAdd(&cnt[d], 1);
    }
}

__global__ void deg_finish_kernel(float* __restrict__ deg, int n3) {
    int i = blockIdx.x * blockDim.x + threadIdx.x;
    if (i < n3) deg[i] = rsqrtf(deg[i]);   // deg >= 1 always (self loop)
}

// ---------------------------------------------------------------------------
// Exclusive prefix sum; one block per edge set (grid.x = 3).
// ---------------------------------------------------------------------------
__global__ __launch_bounds__(1024) void scan_all(const int* __restrict__ cnt3,
                                                 int* __restrict__ rowstart3,
                                                 int* __restrict__ cursor3) {
    const int* cnt = cnt3 + blockIdx.x * N_NODES;
    int* row_start = rowstart3 + blockIdx.x * (N_NODES + 2);
    int* cursor = cursor3 + blockIdx.x * N_NODES;
    __shared__ int part[1024];
    int t = threadIdx.x;
    int base = t * 16;
    int local[16];
    int s = 0;
#pragma unroll
    for (int i = 0; i < 16; ++i) { local[i] = cnt[base + i]; s += local[i]; }
    part[t] = s;
    __syncthreads();
    for (int off = 1; off < 1024; off <<= 1) {
        int v = (t >= off) ? part[t - off] : 0;
        __syncthreads();
        part[t] += v;
        __syncthreads();
    }
    int pre = (t > 0) ? part[t - 1] : 0;
#pragma unroll
    for (int i = 0; i < 16; ++i) {
        row_start[base + i] = pre;
        cursor[base + i] = pre;
        pre += local[i];
    }
    if (t == 1023) row_start[N_NODES] = pre;
}

// Scatter edges into CSR slots; precompute norm = dinv[s]*w*dinv[d].
__global__ void scatter_all(const int* __restrict__ s0, const int* __restrict__ s1,
                            const int* __restrict__ s2,
                            const float* __restrict__ e0, const float* __restrict__ e1,
                            const float* __restrict__ e2,
                            const float* __restrict__ dinv3,
                            int* __restrict__ cursor3,
                            int* __restrict__ csrsrc3, float* __restrict__ csrnorm3,
                            int E) {
    int t = blockIdx.y;
    const int* ed = (t == 0) ? s0 : (t == 1) ? s1 : s2;   // [2][E]: src row then dst row
    const float* ew = (t == 0) ? e0 : (t == 1) ? e1 : e2;
    const float* dinv = dinv3 + t * N_NODES;
    int* cursor = cursor3 + t * N_NODES;
    int* csr_src = csrsrc3 + (size_t)t * E;
    float* csr_norm = csrnorm3 + (size_t)t * E;
    int e = blockIdx.x * blockDim.x + threadIdx.x;
    if (e >= E) return;
    int s = ed[e], d = ed[E + e];
    int pos = atomicAdd(&cursor[d], 1);
    csr_src[pos] = s;
    csr_norm[pos] = dinv[s] * ew[e] * dinv[d];
}

// ---------------------------------------------------------------------------
// Weight pre-pack: WT[n][k] = bf16(W[k][n]) for all 6 weights (grid.z = widx).
// 16x16 LDS tile transpose so both read and write are coalesced.
// ---------------------------------------------------------------------------
__global__ __launch_bounds__(256) void wpack_kernel(const float* __restrict__ w0,
                                                    const float* __restrict__ w1,
                                                    const float* __restrict__ w2,
                                                    const float* __restrict__ w3,
                                                    const float* __restrict__ w4,
                                                    const float* __restrict__ w5,
                                                    ushort* __restrict__ wt) {
    const float* W;
    switch (blockIdx.z) {
        case 0: W = w0; break; case 1: W = w1; break; case 2: W = w2; break;
        case 3: W = w3; break; case 4: W = w4; break; default: W = w5; break;
    }
    __shared__ float tl[16][17];
    int tx = threadIdx.x & 15, ty = threadIdx.x >> 4;
    int k0 = blockIdx.x * 16, n0 = blockIdx.y * 16;
    tl[ty][tx] = W[(size_t)(k0 + ty) * FM + n0 + tx];
    __syncthreads();
    // write WT row n = n0+ty, cols k = k0+tx
    wt[(size_t)blockIdx.z * FM * FM + (size_t)(n0 + ty) * FM + k0 + tx] = f2bf(tl[tx][ty]);
}

// ---------------------------------------------------------------------------
// bf16 MFMA GEMM: C_bf16[M,256] = A_f32[M,256] @ W  (W given as WT[n][k] bf16).
// BM=128, BN=64, BK=64; 256 threads = 4 waves (2x2); wave tile 64x32
// (4x2 fragments of 16x16, K-steps of 32 via mfma_f32_16x16x32_bf16).
// A staged fp32->bf16 in XOR-swizzled LDS (kills stride-128B bank conflicts);
// B fragments read directly from L2-resident WT (128 KB).
// ---------------------------------------------------------------------------
__global__ __launch_bounds__(256) void gemm_mfma(const float* __restrict__ A,
                                                 const ushort* __restrict__ WT,
                                                 ushort* __restrict__ C) {
    __shared__ ushort A_lds[128 * 64];   // [row][k] bf16, 16B-granule XOR swizzle

    const int tid = threadIdx.x;
    const int lane = tid & 63;
    const int wid = tid >> 6;            // 0..3
    const int wm = wid >> 1, wn = wid & 1;
    const int bm = blockIdx.x * 128;
    const int bn = blockIdx.y * 64;

    const int l15 = lane & 15;
    const int lg = lane >> 4;            // k-group 0..3

    f32x4 acc[4][2];
#pragma unroll
    for (int i = 0; i < 4; ++i)
#pragma unroll
        for (int n = 0; n < 2; ++n) acc[i][n] = (f32x4){0.f, 0.f, 0.f, 0.f};

    const int srow = tid >> 1;           // staging row 0..127
    const int shk = tid & 1;             // k-half 0/1 (32 cols each)
    const float* arow_p = &A[(size_t)(bm + srow) * FM + shk * 32];

    for (int k0 = 0; k0 < 256; k0 += 64) {
        // ---- stage A tile [128][64] fp32 -> bf16 swizzled LDS ----
        {
            const float* ap = arow_p + k0;
#pragma unroll
            for (int g = 0; g < 4; ++g) {
                float4 a0 = *(const float4*)(ap + g * 8);
                float4 a1 = *(const float4*)(ap + g * 8 + 4);
                uint4 pk;
                pk.x = pack2bf(a0.x, a0.y);
                pk.y = pack2bf(a0.z, a0.w);
                pk.z = pack2bf(a1.x, a1.y);
                pk.w = pack2bf(a1.z, a1.w);
                int kk = shk * 32 + g * 8;
                int idx = srow * 64 + (kk ^ ((srow & 7) << 3));
                *(uint4*)&A_lds[idx] = pk;
            }
        }
        __syncthreads();
        // ---- 2 k-steps of 32 ----
#pragma unroll
        for (int s = 0; s < 2; ++s) {
            short8 bfrag[2];
#pragma unroll
            for (int n = 0; n < 2; ++n) {
                int col = bn + wn * 32 + n * 16 + l15;
                bfrag[n] = *(const short8*)&WT[(size_t)col * FM + k0 + s * 32 + lg * 8];
            }
#pragma unroll
            for (int i = 0; i < 4; ++i) {
                int row = wm * 64 + i * 16 + l15;
                int kk = s * 32 + lg * 8;
                short8 afrag = *(const short8*)&A_lds[row * 64 + (kk ^ ((row & 7) << 3))];
#pragma unroll
                for (int n = 0; n < 2; ++n)
                    acc[i][n] = __builtin_amdgcn_mfma_f32_16x16x32_bf16(
                        afrag, bfrag[n], acc[i][n], 0, 0, 0);
            }
        }
        __syncthreads();
    }
    // ---- epilogue: C[row][col] bf16; D layout col=lane&15, row=(lane>>4)*4+r
#pragma unroll
    for (int i = 0; i < 4; ++i) {
#pragma unroll
        for (int n = 0; n < 2; ++n) {
            int col = bn + wn * 32 + n * 16 + l15;
#pragma unroll
            for (int r = 0; r < 4; ++r) {
                int row = bm + wm * 64 + i * 16 + lg * 4 + r;
                C[(size_t)row * FM + col] = f2bf(acc[i][n][r]);
            }
        }
    }
}

// ---------------------------------------------------------------------------
// Fused GCN aggregation (CSR, gather-by-destination) over bf16 h:
// out[d][:] = relu( b + dinv[d]^2 * h[d][:] + sum_j norm_j * h[src_j][:] )
// One wave per node; lane l owns 4 bf16 (8B) of the 512B feature row.
// ---------------------------------------------------------------------------
__global__ __launch_bounds__(256) void gcn_aggregate_csr(const ushort* __restrict__ h,
                                                         const int* __restrict__ row_start,
                                                         const int* __restrict__ csr_src,
                                                         const float* __restrict__ csr_norm,
                                                         const float* __restrict__ dinv,
                                                         const float* __restrict__ bias,
                                                         float* __restrict__ out) {
    int node = blockIdx.x * 4 + (threadIdx.x >> 6);
    int lane = threadIdx.x & 63;
    const ushort4* hp = (const ushort4*)h;   // 64 ushort4 per row

    float di = dinv[node];
    float sw = di * di;
    ushort4 q = hp[(size_t)node * 64 + lane];
    float4 accA = make_float4(bf2f(q.x) * sw, bf2f(q.y) * sw,
                              bf2f(q.z) * sw, bf2f(q.w) * sw);
    float4 accB = make_float4(0.f, 0.f, 0.f, 0.f);

    int beg = row_start[node];
    int end = row_start[node + 1];
    int j = beg;
    for (; j + 3 < end; j += 4) {
        int s0 = csr_src[j];
        int s1 = csr_src[j + 1];
        int s2 = csr_src[j + 2];
        int s3 = csr_src[j + 3];
        float w0 = csr_norm[j];
        float w1 = csr_norm[j + 1];
        float w2 = csr_norm[j + 2];
        float w3 = csr_norm[j + 3];
        ushort4 q0 = hp[(size_t)s0 * 64 + lane];
        ushort4 q1 = hp[(size_t)s1 * 64 + lane];
        ushort4 q2 = hp[(size_t)s2 * 64 + lane];
        ushort4 q3 = hp[(size_t)s3 * 64 + lane];
        accA.x += w0 * bf2f(q0.x) + w1 * bf2f(q1.x);
        accA.y += w0 * bf2f(q0.y) + w1 * bf2f(q1.y);
        accA.z += w0 * bf2f(q0.z) + w1 * bf2f(q1.z);
        accA.w += w0 * bf2f(q0.w) + w1 * bf2f(q1.w);
        accB.x += w2 * bf2f(q2.x) + w3 * bf2f(q3.x);
        accB.y += w2 * bf2f(q2.y) + w3 * bf2f(q3.y);
        accB.z += w2 * bf2f(q2.z) + w3 * bf2f(q3.z);
        accB.w += w2 * bf2f(q2.w) + w3 * bf2f(q3.w);
    }
    for (; j < end; ++j) {
        int s0 = csr_src[j];
        float w0 = csr_norm[j];
        ushort4 q0 = hp[(size_t)s0 * 64 + lane];
        accA.x += w0 * bf2f(q0.x);
        accA.y += w0 * bf2f(q0.y);
        accA.z += w0 * bf2f(q0.z);
        accA.w += w0 * bf2f(q0.w);
    }
    float4 bb = ((const float4*)bias)[lane];
    float4 acc;
    acc.x = fmaxf(accA.x + accB.x + bb.x, 0.0f);
    acc.y = fmaxf(accA.y + accB.y + bb.y, 0.0f);
    acc.z = fmaxf(accA.z + accB.z + bb.z, 0.0f);
    acc.w = fmaxf(accA.w + accB.w + bb.w, 0.0f);
    ((float4*)out)[(size_t)node * 64 + lane] = acc;
}

// ---------------------------------------------------------------------------
// SE attention
// ---------------------------------------------------------------------------
__global__ __launch_bounds__(256) void reduce_branch_kernel(const float* __restrict__ br,
                                                            float* __restrict__ pooled) {
    int c = blockIdx.y;
    const float4* p = (const float4*)(br + (size_t)c * NF + (size_t)blockIdx.x * 16384);
    float s = 0.0f;
#pragma unroll
    for (int i = 0; i < 16; ++i) {
        float4 v = p[threadIdx.x + i * 256];
        s += v.x + v.y + v.z + v.w;
    }
    for (int o = 32; o > 0; o >>= 1) s += __shfl_down(s, o);
    __shared__ float wsum[4];
    if ((threadIdx.x & 63) == 0) wsum[threadIdx.x >> 6] = s;
    __syncthreads();
    if (threadIdx.x == 0)
        atomicAdd(&pooled[c], wsum[0] + wsum[1] + wsum[2] + wsum[3]);
}

__global__ void se_kernel(const float* __restrict__ pooled_sum,
                          const float* __restrict__ fc1_w, const float* __restrict__ fc1_b,
                          const float* __restrict__ fc2_w, const float* __restrict__ fc2_b,
                          float* __restrict__ att) {
    __shared__ float p[6];
    __shared__ float hbuf[30];
    int t = threadIdx.x;
    if (t < 6) p[t] = pooled_sum[t] * (1.0f / ((float)N_NODES * (float)FM));
    __syncthreads();
    if (t < 30) {
        float a = fc1_b[t];
#pragma unroll
        for (int c = 0; c < 6; ++c) a += fc1_w[t * 6 + c] * p[c];
        hbuf[t] = fmaxf(a, 0.0f);
    }
    __syncthreads();
    if (t < 6) {
        float a = fc2_b[t];
#pragma unroll
        for (int j = 0; j < 30; ++j) a += fc2_w[t * 30 + j] * hbuf[j];
        att[t] = 1.0f / (1.0f + expf(-a));
    }
}

// out[n][f] = sum_c cnn_w[c] * relu(att[c] * br_c[n][f]) + cnn_b
__global__ void combine_kernel(const float* __restrict__ br,
                               const float* __restrict__ att,
                               const float* __restrict__ cnn_w,
                               const float* __restrict__ cnn_b,
                               float* __restrict__ out, int total4) {
    int i = blockIdx.x * blockDim.x + threadIdx.x;
    if (i >= total4) return;
    float a[6], w[6];
#pragma unroll
    for (int c = 0; c < 6; ++c) { a[c] = att[c]; w[c] = cnn_w[c]; }
    float cb = cnn_b[0];
    float4 acc = make_float4(cb, cb, cb, cb);
#pragma unroll
    for (int c = 0; c < 6; ++c) {
        float4 v = ((const float4*)(br + (size_t)c * NF))[i];
        acc.x += w[c] * fmaxf(a[c] * v.x, 0.0f);
        acc.y += w[c] * fmaxf(a[c] * v.y, 0.0f);
        acc.z += w[c] * fmaxf(a[c] * v.z, 0.0f);
        acc.w += w[c] * fmaxf(a[c] * v.w, 0.0f);
    }
    ((float4*)out)[i] = acc;
}

// ---------------------------------------------------------------------------
// Host orchestration
// ---------------------------------------------------------------------------

static void run_conv(const float* in, const ushort* wtp, const float* b,
                     const int* row_start, const int* csr_src, const float* csr_norm,
                     const float* dinv, ushort* h_bf16, float* out,
                     hipStream_t stream) {
    dim3 ggrid(N_NODES / 128, FM / 64);
    gemm_mfma<<<ggrid, 256, 0, stream>>>(in, wtp, h_bf16);
    gcn_aggregate_csr<<<N_NODES / 4, 256, 0, stream>>>(h_bf16, row_start, csr_src,
                                                       csr_norm, dinv, b, out);
}

extern "C" void kernel_launch(void* const* d_in, const int* in_sizes, int n_in,
                              void* d_out, int out_size, void* d_ws, size_t ws_size,
                              hipStream_t stream) {
    const float* x      = (const float*)d_in[0];
    const int*   ed_f   = (const int*)d_in[1];
    const float* ew_f   = (const float*)d_in[2];
    const int*   ed_s   = (const int*)d_in[3];
    const float* ew_s   = (const float*)d_in[4];
    const int*   ed_g   = (const int*)d_in[5];
    const float* ew_g   = (const float*)d_in[6];
    const float* Wf1 = (const float*)d_in[7];  const float* bf1 = (const float*)d_in[8];
    const float* Wf2 = (const float*)d_in[9];  const float* bf2 = (const float*)d_in[10];
    const float* Ws1 = (const float*)d_in[11]; const float* bs1 = (const float*)d_in[12];
    const float* Ws2 = (const float*)d_in[13]; const float* bs2 = (const float*)d_in[14];
    const float* Wg1 = (const float*)d_in[15]; const float* bg1 = (const float*)d_in[16];
    const float* Wg2 = (const float*)d_in[17]; const float* bg2 = (const float*)d_in[18];
    const float* fc1_w = (const float*)d_in[19]; const float* fc1_b = (const float*)d_in[20];
    const float* fc2_w = (const float*)d_in[21]; const float* fc2_b = (const float*)d_in[22];
    const float* cnn_w = (const float*)d_in[23]; const float* cnn_b = (const float*)d_in[24];

    const int E = in_sizes[1] / 2;   // 524288

    // Workspace layout (4B elements unless noted):
    float* ws = (float*)d_ws;
    float* br = ws;                                    // 6 * NF floats
    float* dinv3  = ws + (size_t)6 * NF;               // 3 * N_NODES
    float* pooled = dinv3 + 3 * N_NODES;               // 6
    float* att    = pooled + 6;                        // 6 (+4 pad)
    int*   cnt3      = (int*)(att + 10);               // 3 * N_NODES
    int*   cursor3   = cnt3 + 3 * N_NODES;             // 3 * N_NODES
    int*   rowstart3 = cursor3 + 3 * N_NODES;          // 3 * (N_NODES+2)
    int*   csr_src3  = rowstart3 + 3 * (N_NODES + 2);  // 3 * E
    float* csr_norm3 = (float*)(csr_src3 + (size_t)3 * E);  // 3 * E
    ushort* wt       = (ushort*)(csr_norm3 + (size_t)3 * E); // 6 * 65536 bf16

    float* dinv_set[3] = { dinv3, dinv3 + N_NODES, dinv3 + 2 * N_NODES };
    int*   rs_set[3]   = { rowstart3, rowstart3 + (N_NODES + 2),
                           rowstart3 + 2 * (N_NODES + 2) };
    int*   csrc_set[3] = { csr_src3, csr_src3 + E, csr_src3 + 2 * E };
    float* cnorm_set[3] = { csr_norm3, csr_norm3 + E, csr_norm3 + 2 * E };

    float* f1 = br + (size_t)0 * NF;
    float* f2 = br + (size_t)1 * NF;
    float* s1 = br + (size_t)2 * NF;
    float* s2 = br + (size_t)3 * NF;
    float* g1 = br + (size_t)4 * NF;
    float* g2 = br + (size_t)5 * NF;

    ushort* h = (ushort*)d_out;   // bf16 GEMM scratch (8MB of the 16MB out buf);
                                  // fully overwritten by combine at the end

    // --- init + degree + CSR build for the 3 edge sets (batched) ---
    int n3 = 3 * N_NODES;
    init_kernel<<<(n3 + 6 + 255) / 256, 256, 0, stream>>>(dinv3, cnt3, pooled);
    {
        dim3 dg((E + 255) / 256, 3);
        deg_edges_all<<<dg, 256, 0, stream>>>(ed_f + E, ed_s + E, ed_g + E,
                                              ew_f, ew_s, ew_g, dinv3, cnt3, E);
    }
    deg_finish_kernel<<<(n3 + 255) / 256, 256, 0, stream>>>(dinv3, n3);
    scan_all<<<3, 1024, 0, stream>>>(cnt3, rowstart3, cursor3);
    {
        dim3 sg((E + 255) / 256, 3);
        scatter_all<<<sg, 256, 0, stream>>>(ed_f, ed_s, ed_g, ew_f, ew_s, ew_g,
                                            dinv3, cursor3, csr_src3, csr_norm3, E);
    }
    // --- weight pre-pack (bf16, transposed) ---
    {
        dim3 wg(16, 16, 6);
        wpack_kernel<<<wg, 256, 0, stream>>>(Wf1, Wf2, Ws1, Ws2, Wg1, Wg2, wt);
    }
    const ushort* wt_set[6] = { wt, wt + 65536, wt + 2 * 65536,
                                wt + 3 * 65536, wt + 4 * 65536, wt + 5 * 65536 };

    // --- six GCN convs ---
    run_conv(x,  wt_set[0], bf1, rs_set[0], csrc_set[0], cnorm_set[0], dinv_set[0], h, f1, stream);
    run_conv(f1, wt_set[1], bf2, rs_set[0], csrc_set[0], cnorm_set[0], dinv_set[0], h, f2, stream);
    run_conv(x,  wt_set[2], bs1, rs_set[1], csrc_set[1], cnorm_set[1], dinv_set[1], h, s1, stream);
    run_conv(s1, wt_set[3], bs2, rs_set[1], csrc_set[1], cnorm_set[1], dinv_set[1], h, s2, stream);
    run_conv(x,  wt_set[4], bg1, rs_set[2], csrc_set[2], cnorm_set[2], dinv_set[2], h, g1, stream);
    run_conv(g1, wt_set[5], bg2, rs_set[2], csrc_set[2], cnorm_set[2], dinv_set[2], h, g2, stream);

    // --- SE attention ---
    dim3 rgrid(256, 6);
    reduce_branch_kernel<<<rgrid, 256, 0, stream>>>(br, pooled);
    se_kernel<<<1, 64, 0, stream>>>(pooled, fc1_w, fc1_b, fc2_w, fc2_b, att);

    // --- final 1x1 conv combine ---
    combine_kernel<<<NF4 / 256, 256, 0, stream>>>(br, att, cnn_w, cnn_b,
                                                  (float*)d_out, NF4);
}